// Round 1
// baseline (2239.143 us; speedup 1.0000x reference)
//
#include <hip/hip_runtime.h>
#include <hip/hip_bf16.h>
#include <hip/hip_fp16.h>

typedef _Float16 f16;
typedef f16 f16x8 __attribute__((ext_vector_type(8)));
typedef float f32x4 __attribute__((ext_vector_type(4)));

#define LL 512
#define BB 32
#define DD 512
#define MM (LL * BB) /* 16384 */

// ---------------- transpose+convert: fp32 (K,N) -> f16 (N,K) ----------------
__global__ __launch_bounds__(256) void k_transpose(const float* __restrict__ in,
                                                   f16* __restrict__ out, int K, int N) {
  __shared__ float tile[32][33];
  size_t bo = (size_t)blockIdx.z * K * N;
  in += bo; out += bo;
  int n0 = blockIdx.x * 32, k0 = blockIdx.y * 32;
  int tx = threadIdx.x, ty = threadIdx.y;
#pragma unroll
  for (int s = 0; s < 4; ++s)
    tile[ty + s * 8][tx] = in[(size_t)(k0 + ty + s * 8) * N + n0 + tx];
  __syncthreads();
#pragma unroll
  for (int s = 0; s < 4; ++s)
    out[(size_t)(n0 + ty + s * 8) * K + k0 + tx] = (f16)tile[tx][ty + s * 8];
}

// ---------------- lin1: y = relu(x @ w + b), x (M,72), w (72,512) ----------------
__global__ __launch_bounds__(256) void k_lin1(const float* __restrict__ x,
                                              const float* __restrict__ w,
                                              const float* __restrict__ bias,
                                              float* __restrict__ y) {
  __shared__ float xs[8][72];
  int m0 = blockIdx.x * 8;
  int t = threadIdx.x;
  if (t < 144) {  // 8 rows * 18 float4 = 144
    int row = t / 18, c4 = (t % 18) * 4;
    float4 v = *(const float4*)(x + (size_t)(m0 + row) * 72 + c4);
    xs[row][c4] = v.x; xs[row][c4 + 1] = v.y; xs[row][c4 + 2] = v.z; xs[row][c4 + 3] = v.w;
  }
  __syncthreads();
  int j0 = t, j1 = t + 256;
  float b0 = bias[j0], b1 = bias[j1];
  float acc[8][2];
#pragma unroll
  for (int r = 0; r < 8; ++r) { acc[r][0] = b0; acc[r][1] = b1; }
  for (int k = 0; k < 72; ++k) {
    float w0 = w[k * 512 + j0], w1 = w[k * 512 + j1];
#pragma unroll
    for (int r = 0; r < 8; ++r) {
      acc[r][0] = fmaf(xs[r][k], w0, acc[r][0]);
      acc[r][1] = fmaf(xs[r][k], w1, acc[r][1]);
    }
  }
#pragma unroll
  for (int r = 0; r < 8; ++r) {
    y[(size_t)(m0 + r) * 512 + j0] = fmaxf(acc[r][0], 0.f);
    y[(size_t)(m0 + r) * 512 + j1] = fmaxf(acc[r][1], 0.f);
  }
}

// ---------------- LayerNorm fp32 -> f16 (one block per row) ----------------
template <int W>
__global__ __launch_bounds__(256) void k_ln(const float* __restrict__ in,
                                            const float* __restrict__ g,
                                            const float* __restrict__ be,
                                            f16* __restrict__ out) {
  constexpr int V = W / 256;  // 2 or 4
  int row = blockIdx.x, t = threadIdx.x;
  const float* p = in + (size_t)row * W;
  float v[V];
  if constexpr (V == 4) {
    float4 x4 = ((const float4*)p)[t];
    v[0] = x4.x; v[1] = x4.y; v[2] = x4.z; v[3] = x4.w;
  } else {
    float2 x2 = ((const float2*)p)[t];
    v[0] = x2.x; v[1] = x2.y;
  }
  float s = 0.f, ss = 0.f;
#pragma unroll
  for (int i = 0; i < V; ++i) { s += v[i]; ss += v[i] * v[i]; }
#pragma unroll
  for (int o = 32; o > 0; o >>= 1) { s += __shfl_down(s, o); ss += __shfl_down(ss, o); }
  __shared__ float red[10];
  if ((t & 63) == 0) { red[(t >> 6) * 2] = s; red[(t >> 6) * 2 + 1] = ss; }
  __syncthreads();
  if (t == 0) {
    float S = red[0] + red[2] + red[4] + red[6];
    float SS = red[1] + red[3] + red[5] + red[7];
    float mean = S / W;
    float var = SS / W - mean * mean;
    red[8] = mean; red[9] = rsqrtf(var + 1e-5f);
  }
  __syncthreads();
  float mean = red[8], rstd = red[9];
  if constexpr (V == 4) {
    union { f16 h[4]; uint2 u; } pk;
#pragma unroll
    for (int i = 0; i < V; ++i) {
      int col = t * V + i;
      pk.h[i] = (f16)((v[i] - mean) * rstd * g[col] + be[col]);
    }
    *(uint2*)(out + (size_t)row * W + t * 4) = pk.u;
  } else {
    union { f16 h[2]; unsigned int u; } pk;
#pragma unroll
    for (int i = 0; i < V; ++i) {
      int col = t * V + i;
      pk.h[i] = (f16)((v[i] - mean) * rstd * g[col] + be[col]);
    }
    *(unsigned int*)(out + (size_t)row * W + t * 2) = pk.u;
  }
}

// ---------------- GEMM: C(M,N) f16 = A(M,K) f16 @ BT(N,K)^T f16 ----------------
// 128x128 tile, BK=32, 4 waves, each wave a 64x64 quadrant of 4x4 16x16x32 MFMAs.
template <int K>
__global__ __launch_bounds__(256, 2) void k_gemm(const f16* __restrict__ A,
                                                 const f16* __restrict__ BT,
                                                 f16* __restrict__ C, int N) {
  __shared__ __align__(16) f16 lA[128][40];  // +8 pad: frag reads land 2-way (free)
  __shared__ __align__(16) f16 lB[128][40];
  int n0 = blockIdx.x * 128, m0 = blockIdx.y * 128;
  int tid = threadIdx.x;
  int lane = tid & 63, wave = tid >> 6;
  int wr = wave >> 1, wc = wave & 1;
  f32x4 acc[4][4] = {};

  int s_row = tid >> 1;          // 0..127
  int s_k = (tid & 1) * 16;      // 0 or 16 (each thread stages 32B = 16 f16)
  const f16* Ap = A + (size_t)(m0 + s_row) * K + s_k;
  const f16* Bp = BT + (size_t)(n0 + s_row) * K + s_k;
  int kq = (lane >> 4) * 8;      // K-chunk of this lane's fragment
  int fr = lane & 15;            // row (A) / col (B) within 16

  for (int k0 = 0; k0 < K; k0 += 32) {
    uint4 a0 = *(const uint4*)(Ap + k0);
    uint4 a1 = *(const uint4*)(Ap + k0 + 8);
    uint4 b0 = *(const uint4*)(Bp + k0);
    uint4 b1 = *(const uint4*)(Bp + k0 + 8);
    __syncthreads();
    *(uint4*)&lA[s_row][s_k] = a0;
    *(uint4*)&lA[s_row][s_k + 8] = a1;
    *(uint4*)&lB[s_row][s_k] = b0;
    *(uint4*)&lB[s_row][s_k + 8] = b1;
    __syncthreads();
    f16x8 af[4], bf[4];
#pragma unroll
    for (int i = 0; i < 4; ++i) af[i] = *(const f16x8*)&lA[wr * 64 + i * 16 + fr][kq];
#pragma unroll
    for (int j = 0; j < 4; ++j) bf[j] = *(const f16x8*)&lB[wc * 64 + j * 16 + fr][kq];
#pragma unroll
    for (int i = 0; i < 4; ++i)
#pragma unroll
      for (int j = 0; j < 4; ++j)
        acc[i][j] = __builtin_amdgcn_mfma_f32_16x16x32_f16(af[i], bf[j], acc[i][j], 0, 0, 0);
  }
  // C/D layout (guide-verified): col = lane&15, row = (lane>>4)*4 + reg
  int col = n0 + wc * 64 + fr;
  int rb = m0 + wr * 64 + (lane >> 4) * 4;
#pragma unroll
  for (int i = 0; i < 4; ++i)
#pragma unroll
    for (int j = 0; j < 4; ++j)
#pragma unroll
      for (int r = 0; r < 4; ++r)
        C[(size_t)(rb + i * 16 + r) * N + col + j * 16] = (f16)acc[i][j][r];
}

// ---------------- SRU scan: one thread per (dir,b,d), 512 sequential steps ----------------
// U: (M, 2*D*KK) f16 from GEMM. dir=1 walks rows in reverse (matches output reversal).
template <int KK>
__global__ __launch_bounds__(64) void k_scan(const f16* __restrict__ U,
                                             const f16* __restrict__ xln,
                                             const float* __restrict__ wcp,
                                             const float* __restrict__ bp,
                                             float* __restrict__ yout,
                                             float* __restrict__ cs) {
  int tid = blockIdx.x * 64 + threadIdx.x;  // 0..32767
  int dir = tid >> 14;
  int b = (tid >> 9) & 31;
  int d = tid & 511;
  int col = dir * 512 + d;
  const int N = 2 * DD * KK;
  float wcf = wcp[dir * 512 + d], wcr = wcp[1024 + dir * 512 + d];
  float bf = bp[dir * 512 + d], br = bp[1024 + dir * 512 + d];
  float c = 0.f;
  for (int t = 0; t < 512; ++t) {
    int rsrc = dir ? (511 - t) : t;
    size_t row = (size_t)rsrc * 32 + b;
    const f16* up = U + row * N + dir * (DD * KK) + d * KK;
    float u0, u1, u2, res;
    if constexpr (KK == 4) {
      uint2 pk = *(const uint2*)up;  // 8B aligned: offset multiple of 4 elems
      union { unsigned int w[2]; f16 h[4]; } q;
      q.w[0] = pk.x; q.w[1] = pk.y;
      u0 = (float)q.h[0]; u1 = (float)q.h[1]; u2 = (float)q.h[2]; res = (float)q.h[3];
    } else {
      u0 = (float)up[0]; u1 = (float)up[1]; u2 = (float)up[2];
      res = (float)xln[row * 1024 + col];
    }
    float f = 1.f / (1.f + __expf(-(u1 + wcf * c + bf)));
    c = f * c + (1.f - f) * u0;
    float r = 1.f / (1.f + __expf(-(u2 + wcr * c + br)));
    float h = r * c + (1.f - r) * res;
    yout[row * 1024 + col] = h;
  }
  cs[b * 1024 + col] = c;
}

// ---------------- lin2: out(M,144) = y(M,1024) @ w(1024,144) + b ----------------
__global__ __launch_bounds__(256) void k_lin2(const float* __restrict__ y,
                                              const float* __restrict__ w,
                                              const float* __restrict__ bias,
                                              float* __restrict__ out) {
  __shared__ float yr[1024];
  int m = blockIdx.x, t = threadIdx.x;
  ((float4*)yr)[t] = ((const float4*)(y + (size_t)m * 1024))[t];
  __syncthreads();
  if (t < 144) {
    float acc = bias[t];
#pragma unroll 8
    for (int k = 0; k < 1024; ++k) acc = fmaf(yr[k], w[k * 144 + t], acc);
    out[(size_t)m * 144 + t] = acc;
  }
}

extern "C" void kernel_launch(void* const* d_in, const int* in_sizes, int n_in,
                              void* d_out, int out_size, void* d_ws, size_t ws_size,
                              hipStream_t stream) {
  const float* x      = (const float*)d_in[0];
  const float* lin1_w = (const float*)d_in[1];
  const float* lin1_b = (const float*)d_in[2];
  const float* lin2_w = (const float*)d_in[3];
  const float* lin2_b = (const float*)d_in[4];
  const float* W0     = (const float*)d_in[5];
  const float* wc0    = (const float*)d_in[6];
  const float* b0     = (const float*)d_in[7];
  const float* ln0_g  = (const float*)d_in[8];
  const float* ln0_b  = (const float*)d_in[9];
  const float* Wl     = (const float*)d_in[10];
  const float* wcl    = (const float*)d_in[11];
  const float* bl     = (const float*)d_in[12];
  const float* lnl_g  = (const float*)d_in[13];
  const float* lnl_b  = (const float*)d_in[14];
  float* out = (float*)d_out;

  // workspace layout (252 MB total)
  char* ws = (char*)d_ws;
  float* y   = (float*)(ws);                      // (16384,1024) f32, 64 MB (layer0 uses stride 512)
  f16*   A16 = (f16*)(ws + ((size_t)64 << 20));   // (16384,1024) f16, 32 MB (LN output)
  f16*   C16 = (f16*)(ws + ((size_t)96 << 20));   // (16384,4096) f16, 128 MB (U buffer)
  f16*   W0T = (f16*)(ws + ((size_t)224 << 20));  // (4096,512) f16, 4 MB
  f16*   WlT = (f16*)(ws + ((size_t)228 << 20));  // 4 x (3072,1024) f16, 24 MB

  // weight transpose+convert (re-done every call; ws is re-poisoned)
  k_transpose<<<dim3(128, 16, 1), dim3(32, 8), 0, stream>>>(W0, W0T, 512, 4096);
  k_transpose<<<dim3(96, 32, 4), dim3(32, 8), 0, stream>>>(Wl, WlT, 1024, 3072);

  // lin1 + relu -> y (stride 512)
  k_lin1<<<MM / 8, 256, 0, stream>>>(x, lin1_w, lin1_b, y);

  // layer 0 (k=4)
  k_ln<512><<<MM, 256, 0, stream>>>(y, ln0_g, ln0_b, A16);
  k_gemm<512><<<dim3(32, 128), 256, 0, stream>>>(A16, W0T, C16, 4096);
  k_scan<4><<<512, 64, 0, stream>>>(C16, (const f16*)nullptr, wc0, b0, y, out + 2359296);

  // layers 1..4 (k=3)
  for (int i = 0; i < 4; ++i) {
    k_ln<1024><<<MM, 256, 0, stream>>>(y, lnl_g + i * 1024, lnl_b + i * 1024, A16);
    k_gemm<1024><<<dim3(24, 128), 256, 0, stream>>>(A16, WlT + (size_t)i * 3072 * 1024, C16, 3072);
    k_scan<3><<<512, 64, 0, stream>>>(C16, A16, wcl + i * 2048, bl + i * 2048, y,
                                      out + 2359296 + (size_t)(i + 1) * 32768);
  }

  // lin2 -> out
  k_lin2<<<MM, 256, 0, stream>>>(y, lin2_w, lin2_b, out);
}

// Round 4
// 2040.000 us; speedup vs baseline: 1.0976x; 1.0976x over previous
//
#include <hip/hip_runtime.h>
#include <hip/hip_bf16.h>
#include <hip/hip_fp16.h>

typedef _Float16 f16;
typedef f16 f16x8 __attribute__((ext_vector_type(8)));
typedef float f32x4 __attribute__((ext_vector_type(4)));

#define LL 512
#define BB 32
#define DD 512
#define MM (LL * BB) /* 16384 */

// async global->LDS, 16B per lane; lds base must be wave-uniform
__device__ __forceinline__ void gl16(const f16* g, f16* l) {
  __builtin_amdgcn_global_load_lds(
      (const __attribute__((address_space(1))) void*)g,
      (__attribute__((address_space(3))) void*)l, 16, 0, 0);
}

// ---- transpose+convert fp32 (K,N) -> f16 (N,K), with SRU slice-plane permutation ----
// out_row(n): dir = n/PD, w = n%PD, d = w/KS, s = w%KS  ->  dir*PD + s*512 + d  (PD=512*KS)
template <int KS>
__global__ __launch_bounds__(256) void k_transpose_perm(const float* __restrict__ in,
                                                        f16* __restrict__ out, int K, int N) {
  __shared__ float tile[32][33];
  size_t bo = (size_t)blockIdx.z * (size_t)K * N;
  const int PD = 512 * KS;
  int n0 = blockIdx.x * 32, k0 = blockIdx.y * 32;
  int tx = threadIdx.x, ty = threadIdx.y;
#pragma unroll
  for (int s = 0; s < 4; ++s)
    tile[ty + s * 8][tx] = in[bo + (size_t)(k0 + ty + s * 8) * N + n0 + tx];
  __syncthreads();
#pragma unroll
  for (int s = 0; s < 4; ++s) {
    int n = n0 + ty + s * 8;
    int dir = n / PD, w = n % PD;
    int orow = dir * PD + (w % KS) * 512 + (w / KS);
    out[bo + (size_t)orow * K + k0 + tx] = (f16)tile[tx][ty + s * 8];
  }
}

// ---- transpose+convert lin2_w (1024,144) f32 -> (144,1024) f16 ----
__global__ __launch_bounds__(256) void k_transpose2(const float* __restrict__ in,
                                                    f16* __restrict__ out) {
  __shared__ float tile[32][33];
  int n0 = blockIdx.x * 32, k0 = blockIdx.y * 32;
  int tx = threadIdx.x, ty = threadIdx.y;
#pragma unroll
  for (int s = 0; s < 4; ++s) {
    int n = n0 + tx;
    tile[ty + s * 8][tx] = (n < 144) ? in[(size_t)(k0 + ty + s * 8) * 144 + n] : 0.f;
  }
  __syncthreads();
#pragma unroll
  for (int s = 0; s < 4; ++s) {
    int n = n0 + ty + s * 8;
    if (n < 144) out[(size_t)n * 1024 + k0 + tx] = (f16)tile[tx][ty + s * 8];
  }
}

// ---- lin1: y = relu(x @ w + b), x (M,72), w (72,512) ----
__global__ __launch_bounds__(256) void k_lin1(const float* __restrict__ x,
                                              const float* __restrict__ w,
                                              const float* __restrict__ bias,
                                              float* __restrict__ y) {
  __shared__ float xs[8][72];
  int m0 = blockIdx.x * 8;
  int t = threadIdx.x;
  if (t < 144) {
    int row = t / 18, c4 = (t % 18) * 4;
    float4 v = *(const float4*)(x + (size_t)(m0 + row) * 72 + c4);
    xs[row][c4] = v.x; xs[row][c4 + 1] = v.y; xs[row][c4 + 2] = v.z; xs[row][c4 + 3] = v.w;
  }
  __syncthreads();
  int j0 = t, j1 = t + 256;
  float b0 = bias[j0], b1 = bias[j1];
  float acc[8][2];
#pragma unroll
  for (int r = 0; r < 8; ++r) { acc[r][0] = b0; acc[r][1] = b1; }
  for (int k = 0; k < 72; ++k) {
    float w0 = w[k * 512 + j0], w1 = w[k * 512 + j1];
#pragma unroll
    for (int r = 0; r < 8; ++r) {
      acc[r][0] = fmaf(xs[r][k], w0, acc[r][0]);
      acc[r][1] = fmaf(xs[r][k], w1, acc[r][1]);
    }
  }
#pragma unroll
  for (int r = 0; r < 8; ++r) {
    y[(size_t)(m0 + r) * 512 + j0] = fmaxf(acc[r][0], 0.f);
    y[(size_t)(m0 + r) * 512 + j1] = fmaxf(acc[r][1], 0.f);
  }
}

// ---- LayerNorm fp32 -> f16 (one block per row) ----
template <int W>
__global__ __launch_bounds__(256) void k_ln(const float* __restrict__ in,
                                            const float* __restrict__ g,
                                            const float* __restrict__ be,
                                            f16* __restrict__ out) {
  constexpr int V = W / 256;
  int row = blockIdx.x, t = threadIdx.x;
  const float* p = in + (size_t)row * W;
  float v[V];
  if constexpr (V == 4) {
    float4 x4 = ((const float4*)p)[t];
    v[0] = x4.x; v[1] = x4.y; v[2] = x4.z; v[3] = x4.w;
  } else {
    float2 x2 = ((const float2*)p)[t];
    v[0] = x2.x; v[1] = x2.y;
  }
  float s = 0.f, ss = 0.f;
#pragma unroll
  for (int i = 0; i < V; ++i) { s += v[i]; ss += v[i] * v[i]; }
#pragma unroll
  for (int o = 32; o > 0; o >>= 1) { s += __shfl_down(s, o); ss += __shfl_down(ss, o); }
  __shared__ float red[10];
  if ((t & 63) == 0) { red[(t >> 6) * 2] = s; red[(t >> 6) * 2 + 1] = ss; }
  __syncthreads();
  if (t == 0) {
    float S = red[0] + red[2] + red[4] + red[6];
    float SS = red[1] + red[3] + red[5] + red[7];
    float mean = S / W;
    float var = SS / W - mean * mean;
    red[8] = mean; red[9] = rsqrtf(var + 1e-5f);
  }
  __syncthreads();
  float mean = red[8], rstd = red[9];
  if constexpr (V == 4) {
    union { f16 h[4]; uint2 u; } pk;
#pragma unroll
    for (int i = 0; i < V; ++i) {
      int col = t * V + i;
      pk.h[i] = (f16)((v[i] - mean) * rstd * g[col] + be[col]);
    }
    *(uint2*)(out + (size_t)row * W + t * 4) = pk.u;
  } else {
    union { f16 h[2]; unsigned int u; } pk;
#pragma unroll
    for (int i = 0; i < V; ++i) {
      int col = t * V + i;
      pk.h[i] = (f16)((v[i] - mean) * rstd * g[col] + be[col]);
    }
    *(unsigned int*)(out + (size_t)row * W + t * 2) = pk.u;
  }
}

// ---- GEMM (m97 structure): C(M,N) f16 = A(M,K) @ BT(N,K)^T, 128x128 tile, BK=32 ----
template <int K>
__global__ __launch_bounds__(256, 2) void k_gemm(const f16* __restrict__ A,
                                                 const f16* __restrict__ BT,
                                                 f16* __restrict__ C, int N) {
  __shared__ __align__(16) f16 lA[128 * 32];  // linear: row*32 + k (gl_lds requires linear)
  __shared__ __align__(16) f16 lB[128 * 32];
  int n0 = blockIdx.x * 128, m0 = blockIdx.y * 128;
  int tid = threadIdx.x, lane = tid & 63, wave = tid >> 6;
  int wr = wave >> 1, wc = wave & 1;
  int fr = lane & 15, kq = (lane >> 4) * 8;
  f32x4 acc[4][4] = {};

  // staging map: wave w covers rows [w*32, w*32+32); lane l -> row w*32 + q*16 + l/4, k (l%4)*8
  int srow = wave * 32 + (lane >> 2);
  int skel = (lane & 3) * 8;
  const f16* Ap0 = A + (size_t)(m0 + srow) * K + skel;
  const f16* Ap1 = Ap0 + (size_t)16 * K;
  const f16* Bp0 = BT + (size_t)(n0 + srow) * K + skel;
  const f16* Bp1 = Bp0 + (size_t)16 * K;
  f16* lA0 = lA + wave * 1024; f16* lA1 = lA0 + 512;
  f16* lB0 = lB + wave * 1024; f16* lB1 = lB0 + 512;

  for (int k0 = 0; k0 < K; k0 += 32) {
    if (k0) __syncthreads();
    gl16(Ap0 + k0, lA0); gl16(Ap1 + k0, lA1);
    gl16(Bp0 + k0, lB0); gl16(Bp1 + k0, lB1);
    __syncthreads();  // compiler drains vmcnt before barrier
    f16x8 af[4], bf[4];
#pragma unroll
    for (int i = 0; i < 4; ++i) af[i] = *(const f16x8*)&lA[(wr * 64 + i * 16 + fr) * 32 + kq];
#pragma unroll
    for (int j = 0; j < 4; ++j) bf[j] = *(const f16x8*)&lB[(wc * 64 + j * 16 + fr) * 32 + kq];
#pragma unroll
    for (int i = 0; i < 4; ++i)
#pragma unroll
      for (int j = 0; j < 4; ++j)
        acc[i][j] = __builtin_amdgcn_mfma_f32_16x16x32_f16(af[i], bf[j], acc[i][j], 0, 0, 0);
  }
  int col = n0 + wc * 64 + fr;
  int rb = m0 + wr * 64 + (lane >> 4) * 4;
#pragma unroll
  for (int i = 0; i < 4; ++i)
#pragma unroll
    for (int j = 0; j < 4; ++j)
#pragma unroll
      for (int r = 0; r < 4; ++r)
        C[(size_t)(rb + i * 16 + r) * N + col + j * 16] = (f16)acc[i][j][r];
}

// ---- SRU scan, plane-split U layout, 8-deep register prefetch ----
// U cols: dir*(512*KK) + s*512 + d  (s=0 cand, 1 forget, 2 reset, 3 residual)
template <int KK>
__global__ __launch_bounds__(256) void k_scan(const f16* __restrict__ U,
                                              const f16* xln,  // no restrict: may alias y16
                                              const float* __restrict__ wcp,
                                              const float* __restrict__ bp,
                                              float* __restrict__ yout,
                                              f16* y16,
                                              float* __restrict__ cs) {
  int tid = blockIdx.x * 256 + threadIdx.x;  // 0..32767
  int dir = tid >> 14, b = (tid >> 9) & 31, d = tid & 511;
  int col = (dir << 9) + d;
  const int N = 1024 * KK;
  const f16* base = U + dir * (512 * KK) + d;
  const f16* rbase = (KK == 4) ? base + 1536 : xln + col;
  const int rstride = (KK == 4) ? N : 1024;
  float wcf = wcp[col], wcr = wcp[1024 + col];
  float bfv = bp[col], brv = bp[1024 + col];
  float c = 0.f;
  f16 ru0[8], ru1[8], ru2[8], rr[8];
#pragma unroll
  for (int i = 0; i < 8; ++i) {
    int row = (dir ? (511 - i) : i) * 32 + b;
    const f16* p = base + (size_t)row * N;
    ru0[i] = p[0]; ru1[i] = p[512]; ru2[i] = p[1024];
    rr[i] = rbase[(size_t)row * rstride];
  }
  bool w16 = (y16 != nullptr);
  for (int t0 = 0; t0 < 512; t0 += 8) {
#pragma unroll
    for (int i = 0; i < 8; ++i) {
      int t = t0 + i;
      float u0 = (float)ru0[i], u1 = (float)ru1[i], u2 = (float)ru2[i], res = (float)rr[i];
      int tp = t + 8;
      if (tp < 512) {  // prefetch 8 steps ahead (same ring slot)
        int prow = (dir ? (511 - tp) : tp) * 32 + b;
        const f16* p = base + (size_t)prow * N;
        ru0[i] = p[0]; ru1[i] = p[512]; ru2[i] = p[1024];
        rr[i] = rbase[(size_t)prow * rstride];
      }
      float f = 1.f / (1.f + __expf(-(u1 + wcf * c + bfv)));
      c = f * c + (1.f - f) * u0;
      float r = 1.f / (1.f + __expf(-(u2 + wcr * c + brv)));
      float h = r * c + (1.f - r) * res;
      int row = (dir ? (511 - t) : t) * 32 + b;
      if (w16) y16[(size_t)row * 1024 + col] = (f16)h;
      else     yout[(size_t)row * 1024 + col] = h;
    }
  }
  cs[b * 1024 + col] = c;
}

// ---- lin2 via MFMA: out(M,144) f32 = Y(M,1024) f16 @ WT(144,1024)^T + bias ----
__global__ __launch_bounds__(256) void k_lin2m(const f16* __restrict__ Y,
                                               const f16* __restrict__ WT,
                                               const float* __restrict__ bias,
                                               float* __restrict__ out) {
  __shared__ __align__(16) f16 lA[64 * 32];
  int m0 = blockIdx.x * 64;
  int tid = threadIdx.x, lane = tid & 63, wave = tid >> 6;
  int fr = lane & 15, kq = (lane >> 4) * 8;
  f32x4 acc[9] = {};
  int srow = wave * 16 + (lane >> 2);
  int skel = (lane & 3) * 8;
  const f16* Yp = Y + (size_t)(m0 + srow) * 1024 + skel;
  f16* ldst = lA + wave * 512;
  for (int k0 = 0; k0 < 1024; k0 += 32) {
    if (k0) __syncthreads();
    gl16(Yp + k0, ldst);
    f16x8 bf[9];
#pragma unroll
    for (int j = 0; j < 9; ++j)
      bf[j] = *(const f16x8*)(WT + (size_t)(j * 16 + fr) * 1024 + k0 + kq);
    __syncthreads();
    f16x8 af = *(const f16x8*)&lA[(wave * 16 + fr) * 32 + kq];
#pragma unroll
    for (int j = 0; j < 9; ++j)
      acc[j] = __builtin_amdgcn_mfma_f32_16x16x32_f16(af, bf[j], acc[j], 0, 0, 0);
  }
  int rb = m0 + wave * 16 + (lane >> 4) * 4;
#pragma unroll
  for (int j = 0; j < 9; ++j) {
    float bv = bias[j * 16 + fr];
#pragma unroll
    for (int r = 0; r < 4; ++r)
      out[(size_t)(rb + r) * 144 + j * 16 + fr] = acc[j][r] + bv;
  }
}

extern "C" void kernel_launch(void* const* d_in, const int* in_sizes, int n_in,
                              void* d_out, int out_size, void* d_ws, size_t ws_size,
                              hipStream_t stream) {
  const float* x      = (const float*)d_in[0];
  const float* lin1_w = (const float*)d_in[1];
  const float* lin1_b = (const float*)d_in[2];
  const float* lin2_w = (const float*)d_in[3];
  const float* lin2_b = (const float*)d_in[4];
  const float* W0     = (const float*)d_in[5];
  const float* wc0    = (const float*)d_in[6];
  const float* b0     = (const float*)d_in[7];
  const float* ln0_g  = (const float*)d_in[8];
  const float* ln0_b  = (const float*)d_in[9];
  const float* Wl     = (const float*)d_in[10];
  const float* wcl    = (const float*)d_in[11];
  const float* bl     = (const float*)d_in[12];
  const float* lnl_g  = (const float*)d_in[13];
  const float* lnl_b  = (const float*)d_in[14];
  float* out = (float*)d_out;

  // workspace layout (252 MB, proven safe in round 0)
  char* ws = (char*)d_ws;
  float* y   = (float*)(ws);                      // (16384,1024) f32, 64 MB
  f16*   A16 = (f16*)(ws + ((size_t)64 << 20));   // (16384,1024) f16, 32 MB
  f16*   C16 = (f16*)(ws + ((size_t)96 << 20));   // (16384,4096) f16, up to 128 MB
  f16*   WT2 = (f16*)(ws + ((size_t)192 << 20));  // (144,1024) f16, 288 KB (C16 tail; used after layer0)
  f16*   W0T = (f16*)(ws + ((size_t)224 << 20));  // (4096,512) f16, 4 MB
  f16*   WlT = (f16*)(ws + ((size_t)228 << 20));  // 4 x (3072,1024) f16, 24 MB

  k_transpose_perm<4><<<dim3(128, 16, 1), dim3(32, 8), 0, stream>>>(W0, W0T, 512, 4096);
  k_transpose_perm<3><<<dim3(96, 32, 4), dim3(32, 8), 0, stream>>>(Wl, WlT, 1024, 3072);

  k_lin1<<<MM / 8, 256, 0, stream>>>(x, lin1_w, lin1_b, y);

  // layer 0 (k=4)
  k_ln<512><<<MM, 256, 0, stream>>>(y, ln0_g, ln0_b, A16);
  k_gemm<512><<<dim3(32, 128), 256, 0, stream>>>(A16, W0T, C16, 4096);
  k_scan<4><<<128, 256, 0, stream>>>(C16, (const f16*)nullptr, wc0, b0, y, (f16*)nullptr,
                                     out + 2359296);

  // lin2 weight transpose (into C16 tail, now free)
  k_transpose2<<<dim3(5, 32), dim3(32, 8), 0, stream>>>(lin2_w, WT2);

  // layers 1..4 (k=3); final scan emits f16 y in-place into A16 for lin2
  for (int i = 0; i < 4; ++i) {
    k_ln<1024><<<MM, 256, 0, stream>>>(y, lnl_g + i * 1024, lnl_b + i * 1024, A16);
    k_gemm<1024><<<dim3(24, 128), 256, 0, stream>>>(A16, WlT + (size_t)i * 3072 * 1024, C16, 3072);
    k_scan<3><<<128, 256, 0, stream>>>(C16, A16, wcl + i * 2048, bl + i * 2048, y,
                                       (i == 3) ? A16 : (f16*)nullptr,
                                       out + 2359296 + (size_t)(i + 1) * 32768);
  }

  k_lin2m<<<MM / 64, 256, 0, stream>>>(A16, WT2, lin2_b, out);
}

// Round 5
// 1954.372 us; speedup vs baseline: 1.1457x; 1.0438x over previous
//
#include <hip/hip_runtime.h>
#include <hip/hip_bf16.h>
#include <hip/hip_fp16.h>

typedef _Float16 f16;
typedef f16 f16x8 __attribute__((ext_vector_type(8)));
typedef float f32x4 __attribute__((ext_vector_type(4)));

#define LL 512
#define BB 32
#define DD 512
#define MM (LL * BB) /* 16384 */

// async global->LDS, 16B per lane; lds base must be wave-uniform
__device__ __forceinline__ void gl16(const f16* g, f16* l) {
  __builtin_amdgcn_global_load_lds(
      (const __attribute__((address_space(1))) void*)g,
      (__attribute__((address_space(3))) void*)l, 16, 0, 0);
}

// ---- transpose+convert fp32 (K,N) -> f16 (N,K), with SRU slice-plane permutation ----
// out_row(n): dir = n/PD, w = n%PD, d = w/KS, s = w%KS  ->  dir*PD + s*512 + d  (PD=512*KS)
template <int KS>
__global__ __launch_bounds__(256) void k_transpose_perm(const float* __restrict__ in,
                                                        f16* __restrict__ out, int K, int N) {
  __shared__ float tile[32][33];
  size_t bo = (size_t)blockIdx.z * (size_t)K * N;
  const int PD = 512 * KS;
  int n0 = blockIdx.x * 32, k0 = blockIdx.y * 32;
  int tx = threadIdx.x, ty = threadIdx.y;
#pragma unroll
  for (int s = 0; s < 4; ++s)
    tile[ty + s * 8][tx] = in[bo + (size_t)(k0 + ty + s * 8) * N + n0 + tx];
  __syncthreads();
#pragma unroll
  for (int s = 0; s < 4; ++s) {
    int n = n0 + ty + s * 8;
    int dir = n / PD, w = n % PD;
    int orow = dir * PD + (w % KS) * 512 + (w / KS);
    out[bo + (size_t)orow * K + k0 + tx] = (f16)tile[tx][ty + s * 8];
  }
}

// ---- transpose+convert lin2_w (1024,144) f32 -> (144,1024) f16 ----
__global__ __launch_bounds__(256) void k_transpose2(const float* __restrict__ in,
                                                    f16* __restrict__ out) {
  __shared__ float tile[32][33];
  int n0 = blockIdx.x * 32, k0 = blockIdx.y * 32;
  int tx = threadIdx.x, ty = threadIdx.y;
#pragma unroll
  for (int s = 0; s < 4; ++s) {
    int n = n0 + tx;
    tile[ty + s * 8][tx] = (n < 144) ? in[(size_t)(k0 + ty + s * 8) * 144 + n] : 0.f;
  }
  __syncthreads();
#pragma unroll
  for (int s = 0; s < 4; ++s) {
    int n = n0 + ty + s * 8;
    if (n < 144) out[(size_t)n * 1024 + k0 + tx] = (f16)tile[tx][ty + s * 8];
  }
}

// ---- lin1: y = relu(x @ w + b), x (M,72), w (72,512) ----
__global__ __launch_bounds__(256) void k_lin1(const float* __restrict__ x,
                                              const float* __restrict__ w,
                                              const float* __restrict__ bias,
                                              float* __restrict__ y) {
  __shared__ float xs[8][72];
  int m0 = blockIdx.x * 8;
  int t = threadIdx.x;
  if (t < 144) {
    int row = t / 18, c4 = (t % 18) * 4;
    float4 v = *(const float4*)(x + (size_t)(m0 + row) * 72 + c4);
    xs[row][c4] = v.x; xs[row][c4 + 1] = v.y; xs[row][c4 + 2] = v.z; xs[row][c4 + 3] = v.w;
  }
  __syncthreads();
  int j0 = t, j1 = t + 256;
  float b0 = bias[j0], b1 = bias[j1];
  float acc[8][2];
#pragma unroll
  for (int r = 0; r < 8; ++r) { acc[r][0] = b0; acc[r][1] = b1; }
  for (int k = 0; k < 72; ++k) {
    float w0 = w[k * 512 + j0], w1 = w[k * 512 + j1];
#pragma unroll
    for (int r = 0; r < 8; ++r) {
      acc[r][0] = fmaf(xs[r][k], w0, acc[r][0]);
      acc[r][1] = fmaf(xs[r][k], w1, acc[r][1]);
    }
  }
#pragma unroll
  for (int r = 0; r < 8; ++r) {
    y[(size_t)(m0 + r) * 512 + j0] = fmaxf(acc[r][0], 0.f);
    y[(size_t)(m0 + r) * 512 + j1] = fmaxf(acc[r][1], 0.f);
  }
}

// ---- LayerNorm fp32 -> f16 (one block per row) ----
template <int W>
__global__ __launch_bounds__(256) void k_ln(const float* __restrict__ in,
                                            const float* __restrict__ g,
                                            const float* __restrict__ be,
                                            f16* __restrict__ out) {
  constexpr int V = W / 256;
  int row = blockIdx.x, t = threadIdx.x;
  const float* p = in + (size_t)row * W;
  float v[V];
  if constexpr (V == 4) {
    float4 x4 = ((const float4*)p)[t];
    v[0] = x4.x; v[1] = x4.y; v[2] = x4.z; v[3] = x4.w;
  } else {
    float2 x2 = ((const float2*)p)[t];
    v[0] = x2.x; v[1] = x2.y;
  }
  float s = 0.f, ss = 0.f;
#pragma unroll
  for (int i = 0; i < V; ++i) { s += v[i]; ss += v[i] * v[i]; }
#pragma unroll
  for (int o = 32; o > 0; o >>= 1) { s += __shfl_down(s, o); ss += __shfl_down(ss, o); }
  __shared__ float red[10];
  if ((t & 63) == 0) { red[(t >> 6) * 2] = s; red[(t >> 6) * 2 + 1] = ss; }
  __syncthreads();
  if (t == 0) {
    float S = red[0] + red[2] + red[4] + red[6];
    float SS = red[1] + red[3] + red[5] + red[7];
    float mean = S / W;
    float var = SS / W - mean * mean;
    red[8] = mean; red[9] = rsqrtf(var + 1e-5f);
  }
  __syncthreads();
  float mean = red[8], rstd = red[9];
  if constexpr (V == 4) {
    union { f16 h[4]; uint2 u; } pk;
#pragma unroll
    for (int i = 0; i < V; ++i) {
      int col = t * V + i;
      pk.h[i] = (f16)((v[i] - mean) * rstd * g[col] + be[col]);
    }
    *(uint2*)(out + (size_t)row * W + t * 4) = pk.u;
  } else {
    union { f16 h[2]; unsigned int u; } pk;
#pragma unroll
    for (int i = 0; i < V; ++i) {
      int col = t * V + i;
      pk.h[i] = (f16)((v[i] - mean) * rstd * g[col] + be[col]);
    }
    *(unsigned int*)(out + (size_t)row * W + t * 2) = pk.u;
  }
}

// ---- GEMM (m97 structure): C(M,N) f16 = A(M,K) @ BT(N,K)^T, 128x128 tile, BK=32 ----
template <int K>
__global__ __launch_bounds__(256, 2) void k_gemm(const f16* __restrict__ A,
                                                 const f16* __restrict__ BT,
                                                 f16* __restrict__ C, int N) {
  __shared__ __align__(16) f16 lA[128 * 32];  // linear: row*32 + k (gl_lds requires linear)
  __shared__ __align__(16) f16 lB[128 * 32];
  int n0 = blockIdx.x * 128, m0 = blockIdx.y * 128;
  int tid = threadIdx.x, lane = tid & 63, wave = tid >> 6;
  int wr = wave >> 1, wc = wave & 1;
  int fr = lane & 15, kq = (lane >> 4) * 8;
  f32x4 acc[4][4] = {};

  int srow = wave * 32 + (lane >> 2);
  int skel = (lane & 3) * 8;
  const f16* Ap0 = A + (size_t)(m0 + srow) * K + skel;
  const f16* Ap1 = Ap0 + (size_t)16 * K;
  const f16* Bp0 = BT + (size_t)(n0 + srow) * K + skel;
  const f16* Bp1 = Bp0 + (size_t)16 * K;
  f16* lA0 = lA + wave * 1024; f16* lA1 = lA0 + 512;
  f16* lB0 = lB + wave * 1024; f16* lB1 = lB0 + 512;

  for (int k0 = 0; k0 < K; k0 += 32) {
    if (k0) __syncthreads();
    gl16(Ap0 + k0, lA0); gl16(Ap1 + k0, lA1);
    gl16(Bp0 + k0, lB0); gl16(Bp1 + k0, lB1);
    __syncthreads();  // compiler drains vmcnt before barrier
    f16x8 af[4], bf[4];
#pragma unroll
    for (int i = 0; i < 4; ++i) af[i] = *(const f16x8*)&lA[(wr * 64 + i * 16 + fr) * 32 + kq];
#pragma unroll
    for (int j = 0; j < 4; ++j) bf[j] = *(const f16x8*)&lB[(wc * 64 + j * 16 + fr) * 32 + kq];
#pragma unroll
    for (int i = 0; i < 4; ++i)
#pragma unroll
      for (int j = 0; j < 4; ++j)
        acc[i][j] = __builtin_amdgcn_mfma_f32_16x16x32_f16(af[i], bf[j], acc[i][j], 0, 0, 0);
  }
  int col = n0 + wc * 64 + fr;
  int rb = m0 + wr * 64 + (lane >> 4) * 4;
#pragma unroll
  for (int i = 0; i < 4; ++i)
#pragma unroll
    for (int j = 0; j < 4; ++j)
#pragma unroll
      for (int r = 0; r < 4; ++r)
        C[(size_t)(rb + i * 16 + r) * N + col + j * 16] = (f16)acc[i][j][r];
}

// ---- SRU scan, delayed-store prefetch ring (fixes in-order-vmcnt store hazard) ----
// U cols: dir*(512*KK) + s*512 + d. One thread per (dir,b,d). Ring depth 8.
// Store of h(t-8) is issued BEFORE the prefetch of t+8 (sched_barrier-pinned), so the
// waitcnt to reuse hh[i] only requires loads this body consumes anyway.
template <int KK, bool W16>
__global__ __launch_bounds__(64) void k_scan(const f16* __restrict__ U,
                                             const f16* xln,  // no restrict: may alias y16
                                             const float* __restrict__ wcp,
                                             const float* __restrict__ bp,
                                             float* __restrict__ yout,
                                             f16* y16,
                                             float* __restrict__ cs) {
  int tid = blockIdx.x * 64 + threadIdx.x;  // 0..32767
  int dir = tid >> 14, b = (tid >> 9) & 31, d = tid & 511;
  int col = (dir << 9) + d;
  const int N = 1024 * KK;
  const f16* base = U + dir * (512 * KK) + d;
  const f16* rbase = (KK == 4) ? base + 1536 : xln + col;
  const int rstride = (KK == 4) ? N : 1024;
  float wcf = wcp[col], wcr = wcp[1024 + col];
  float bfv = bp[col], brv = bp[1024 + col];
  float c = 0.f;
  f16 ru0[8], ru1[8], ru2[8], rr[8];
  float hh[8];
#pragma unroll
  for (int i = 0; i < 8; ++i) {
    int row = ((dir ? (511 - i) : i) << 5) + b;
    const f16* p = base + (size_t)row * N;
    ru0[i] = p[0]; ru1[i] = p[512]; ru2[i] = p[1024];
    rr[i] = rbase[(size_t)row * rstride];
  }

#define SCAN_BODY(i, t, DO_STORE)                                          \
  {                                                                        \
    float u0 = (float)ru0[i], u1 = (float)ru1[i], u2 = (float)ru2[i],      \
          res = (float)rr[i];                                              \
    if (DO_STORE) {                                                        \
      int so = (t) - 8;                                                    \
      int srw = ((dir ? (511 - so) : so) << 5) + b;                        \
      if (W16) y16[(size_t)srw * 1024 + col] = (f16)hh[i];                 \
      else     yout[(size_t)srw * 1024 + col] = hh[i];                     \
      __builtin_amdgcn_sched_barrier(0); /* pin store before prefetch */   \
    }                                                                      \
    int tp = (t) + 8;                                                      \
    if (tp < 512) {                                                        \
      int prow = ((dir ? (511 - tp) : tp) << 5) + b;                       \
      const f16* p = base + (size_t)prow * N;                              \
      ru0[i] = p[0]; ru1[i] = p[512]; ru2[i] = p[1024];                    \
      rr[i] = rbase[(size_t)prow * rstride];                               \
    }                                                                      \
    float f = 1.f / (1.f + __expf(-(u1 + wcf * c + bfv)));                 \
    c = f * c + (1.f - f) * u0;                                            \
    float r = 1.f / (1.f + __expf(-(u2 + wcr * c + brv)));                 \
    hh[i] = r * c + (1.f - r) * res;                                       \
  }

  // ring cycle 0 (no delayed stores yet)
#pragma unroll
  for (int i = 0; i < 8; ++i) SCAN_BODY(i, i, false);
  // steady state
  for (int t0 = 8; t0 < 512; t0 += 8) {
#pragma unroll
    for (int i = 0; i < 8; ++i) SCAN_BODY(i, t0 + i, true);
  }
  // epilogue: store last ring cycle (t = 504..511)
#pragma unroll
  for (int i = 0; i < 8; ++i) {
    int t = 504 + i;
    int srw = ((dir ? (511 - t) : t) << 5) + b;
    if (W16) y16[(size_t)srw * 1024 + col] = (f16)hh[i];
    else     yout[(size_t)srw * 1024 + col] = hh[i];
  }
  cs[b * 1024 + col] = c;
#undef SCAN_BODY
}

// ---- lin2 via MFMA: out(M,144) f32 = Y(M,1024) f16 @ WT(144,1024)^T + bias ----
__global__ __launch_bounds__(256) void k_lin2m(const f16* __restrict__ Y,
                                               const f16* __restrict__ WT,
                                               const float* __restrict__ bias,
                                               float* __restrict__ out) {
  __shared__ __align__(16) f16 lA[64 * 32];
  int m0 = blockIdx.x * 64;
  int tid = threadIdx.x, lane = tid & 63, wave = tid >> 6;
  int fr = lane & 15, kq = (lane >> 4) * 8;
  f32x4 acc[9] = {};
  int srow = wave * 16 + (lane >> 2);
  int skel = (lane & 3) * 8;
  const f16* Yp = Y + (size_t)(m0 + srow) * 1024 + skel;
  f16* ldst = lA + wave * 512;
  for (int k0 = 0; k0 < 1024; k0 += 32) {
    if (k0) __syncthreads();
    gl16(Yp + k0, ldst);
    f16x8 bf[9];
#pragma unroll
    for (int j = 0; j < 9; ++j)
      bf[j] = *(const f16x8*)(WT + (size_t)(j * 16 + fr) * 1024 + k0 + kq);
    __syncthreads();
    f16x8 af = *(const f16x8*)&lA[(wave * 16 + fr) * 32 + kq];
#pragma unroll
    for (int j = 0; j < 9; ++j)
      acc[j] = __builtin_amdgcn_mfma_f32_16x16x32_f16(af, bf[j], acc[j], 0, 0, 0);
  }
  int rb = m0 + wave * 16 + (lane >> 4) * 4;
#pragma unroll
  for (int j = 0; j < 9; ++j) {
    float bv = bias[j * 16 + fr];
#pragma unroll
    for (int r = 0; r < 4; ++r)
      out[(size_t)(rb + r) * 144 + j * 16 + fr] = acc[j][r] + bv;
  }
}

extern "C" void kernel_launch(void* const* d_in, const int* in_sizes, int n_in,
                              void* d_out, int out_size, void* d_ws, size_t ws_size,
                              hipStream_t stream) {
  const float* x      = (const float*)d_in[0];
  const float* lin1_w = (const float*)d_in[1];
  const float* lin1_b = (const float*)d_in[2];
  const float* lin2_w = (const float*)d_in[3];
  const float* lin2_b = (const float*)d_in[4];
  const float* W0     = (const float*)d_in[5];
  const float* wc0    = (const float*)d_in[6];
  const float* b0     = (const float*)d_in[7];
  const float* ln0_g  = (const float*)d_in[8];
  const float* ln0_b  = (const float*)d_in[9];
  const float* Wl     = (const float*)d_in[10];
  const float* wcl    = (const float*)d_in[11];
  const float* bl     = (const float*)d_in[12];
  const float* lnl_g  = (const float*)d_in[13];
  const float* lnl_b  = (const float*)d_in[14];
  float* out = (float*)d_out;

  // workspace layout (252 MB, proven safe)
  char* ws = (char*)d_ws;
  float* y   = (float*)(ws);                      // (16384,1024) f32, 64 MB
  f16*   A16 = (f16*)(ws + ((size_t)64 << 20));   // (16384,1024) f16, 32 MB
  f16*   C16 = (f16*)(ws + ((size_t)96 << 20));   // (16384,4096) f16, up to 128 MB
  f16*   WT2 = (f16*)(ws + ((size_t)192 << 20));  // (144,1024) f16 (C16 tail; used after layer0)
  f16*   W0T = (f16*)(ws + ((size_t)224 << 20));  // (4096,512) f16, 4 MB
  f16*   WlT = (f16*)(ws + ((size_t)228 << 20));  // 4 x (3072,1024) f16, 24 MB

  k_transpose_perm<4><<<dim3(128, 16, 1), dim3(32, 8), 0, stream>>>(W0, W0T, 512, 4096);
  k_transpose_perm<3><<<dim3(96, 32, 4), dim3(32, 8), 0, stream>>>(Wl, WlT, 1024, 3072);

  k_lin1<<<MM / 8, 256, 0, stream>>>(x, lin1_w, lin1_b, y);

  // layer 0 (k=4)
  k_ln<512><<<MM, 256, 0, stream>>>(y, ln0_g, ln0_b, A16);
  k_gemm<512><<<dim3(32, 128), 256, 0, stream>>>(A16, W0T, C16, 4096);
  k_scan<4, false><<<512, 64, 0, stream>>>(C16, (const f16*)nullptr, wc0, b0, y, (f16*)nullptr,
                                           out + 2359296);

  // lin2 weight transpose (into C16 tail, now free)
  k_transpose2<<<dim3(5, 32), dim3(32, 8), 0, stream>>>(lin2_w, WT2);

  // layers 1..4 (k=3); final scan emits f16 y in-place into A16 for lin2
  for (int i = 0; i < 4; ++i) {
    k_ln<1024><<<MM, 256, 0, stream>>>(y, lnl_g + i * 1024, lnl_b + i * 1024, A16);
    k_gemm<1024><<<dim3(24, 128), 256, 0, stream>>>(A16, WlT + (size_t)i * 3072 * 1024, C16, 3072);
    if (i == 3)
      k_scan<3, true><<<512, 64, 0, stream>>>(C16, A16, wcl + i * 2048, bl + i * 2048, y, A16,
                                              out + 2359296 + (size_t)(i + 1) * 32768);
    else
      k_scan<3, false><<<512, 64, 0, stream>>>(C16, A16, wcl + i * 2048, bl + i * 2048, y,
                                               (f16*)nullptr,
                                               out + 2359296 + (size_t)(i + 1) * 32768);
  }

  k_lin2m<<<MM / 64, 256, 0, stream>>>(A16, WT2, lin2_b, out);
}

// Round 6
// 1124.954 us; speedup vs baseline: 1.9904x; 1.7373x over previous
//
#include <hip/hip_runtime.h>
#include <hip/hip_bf16.h>
#include <hip/hip_fp16.h>

typedef _Float16 f16;
typedef f16 f16x8 __attribute__((ext_vector_type(8)));
typedef float f32x4 __attribute__((ext_vector_type(4)));

#define LL 512
#define BB 32
#define DD 512
#define MM (LL * BB) /* 16384 */

// async global->LDS, 16B per lane; lds base must be wave-uniform
__device__ __forceinline__ void gl16(const f16* g, f16* l) {
  __builtin_amdgcn_global_load_lds(
      (const __attribute__((address_space(1))) void*)g,
      (__attribute__((address_space(3))) void*)l, 16, 0, 0);
}

// ---- transpose+convert fp32 (K,N) -> f16 (N,K), with SRU slice-plane permutation ----
// out_row(n): dir = n/PD, w = n%PD -> dir*PD + (w%KS)*512 + w/KS  (PD=512*KS)
template <int KS>
__global__ __launch_bounds__(256) void k_transpose_perm(const float* __restrict__ in,
                                                        f16* __restrict__ out, int K, int N) {
  __shared__ float tile[32][33];
  size_t bo = (size_t)blockIdx.z * (size_t)K * N;
  const int PD = 512 * KS;
  int n0 = blockIdx.x * 32, k0 = blockIdx.y * 32;
  int tx = threadIdx.x, ty = threadIdx.y;
#pragma unroll
  for (int s = 0; s < 4; ++s)
    tile[ty + s * 8][tx] = in[bo + (size_t)(k0 + ty + s * 8) * N + n0 + tx];
  __syncthreads();
#pragma unroll
  for (int s = 0; s < 4; ++s) {
    int n = n0 + ty + s * 8;
    int dir = n / PD, w = n % PD;
    int orow = dir * PD + (w % KS) * 512 + (w / KS);
    out[bo + (size_t)orow * K + k0 + tx] = (f16)tile[tx][ty + s * 8];
  }
}

// ---- transpose+convert lin2_w (1024,144) f32 -> (144,1024) f16 ----
__global__ __launch_bounds__(256) void k_transpose2(const float* __restrict__ in,
                                                    f16* __restrict__ out) {
  __shared__ float tile[32][33];
  int n0 = blockIdx.x * 32, k0 = blockIdx.y * 32;
  int tx = threadIdx.x, ty = threadIdx.y;
#pragma unroll
  for (int s = 0; s < 4; ++s) {
    int n = n0 + tx;
    tile[ty + s * 8][tx] = (n < 144) ? in[(size_t)(k0 + ty + s * 8) * 144 + n] : 0.f;
  }
  __syncthreads();
#pragma unroll
  for (int s = 0; s < 4; ++s) {
    int n = n0 + ty + s * 8;
    if (n < 144) out[(size_t)n * 1024 + k0 + tx] = (f16)tile[tx][ty + s * 8];
  }
}

// ---- lin1: yH = relu(x @ w + b) as f16, x (M,72), w (72,512) ----
__global__ __launch_bounds__(256) void k_lin1(const float* __restrict__ x,
                                              const float* __restrict__ w,
                                              const float* __restrict__ bias,
                                              f16* __restrict__ yH) {
  __shared__ float xs[8][72];
  int m0 = blockIdx.x * 8;
  int t = threadIdx.x;
  if (t < 144) {
    int row = t / 18, c4 = (t % 18) * 4;
    float4 v = *(const float4*)(x + (size_t)(m0 + row) * 72 + c4);
    xs[row][c4] = v.x; xs[row][c4 + 1] = v.y; xs[row][c4 + 2] = v.z; xs[row][c4 + 3] = v.w;
  }
  __syncthreads();
  int j0 = t, j1 = t + 256;
  float b0 = bias[j0], b1 = bias[j1];
  float acc[8][2];
#pragma unroll
  for (int r = 0; r < 8; ++r) { acc[r][0] = b0; acc[r][1] = b1; }
  for (int k = 0; k < 72; ++k) {
    float w0 = w[k * 512 + j0], w1 = w[k * 512 + j1];
#pragma unroll
    for (int r = 0; r < 8; ++r) {
      acc[r][0] = fmaf(xs[r][k], w0, acc[r][0]);
      acc[r][1] = fmaf(xs[r][k], w1, acc[r][1]);
    }
  }
#pragma unroll
  for (int r = 0; r < 8; ++r) {
    yH[(size_t)(m0 + r) * 512 + j0] = (f16)fmaxf(acc[r][0], 0.f);
    yH[(size_t)(m0 + r) * 512 + j1] = (f16)fmaxf(acc[r][1], 0.f);
  }
}

// ---- LayerNorm f16 -> f16 (one block per row), stats in f32 ----
template <int W>
__global__ __launch_bounds__(256) void k_ln(const f16* __restrict__ in,
                                            const float* __restrict__ g,
                                            const float* __restrict__ be,
                                            f16* __restrict__ out) {
  constexpr int V = W / 256;  // 2 or 4
  int row = blockIdx.x, t = threadIdx.x;
  const f16* p = in + (size_t)row * W + t * V;
  float v[V];
  if constexpr (V == 4) {
    union { uint2 u; f16 h[4]; } pk;
    pk.u = *(const uint2*)p;
#pragma unroll
    for (int i = 0; i < 4; ++i) v[i] = (float)pk.h[i];
  } else {
    union { unsigned u; f16 h[2]; } pk;
    pk.u = *(const unsigned*)p;
    v[0] = (float)pk.h[0]; v[1] = (float)pk.h[1];
  }
  float s = 0.f, ss = 0.f;
#pragma unroll
  for (int i = 0; i < V; ++i) { s += v[i]; ss += v[i] * v[i]; }
#pragma unroll
  for (int o = 32; o > 0; o >>= 1) { s += __shfl_down(s, o); ss += __shfl_down(ss, o); }
  __shared__ float red[10];
  if ((t & 63) == 0) { red[(t >> 6) * 2] = s; red[(t >> 6) * 2 + 1] = ss; }
  __syncthreads();
  if (t == 0) {
    float S = red[0] + red[2] + red[4] + red[6];
    float SS = red[1] + red[3] + red[5] + red[7];
    float mean = S / W;
    float var = SS / W - mean * mean;
    red[8] = mean; red[9] = rsqrtf(var + 1e-5f);
  }
  __syncthreads();
  float mean = red[8], rstd = red[9];
  if constexpr (V == 4) {
    union { f16 h[4]; uint2 u; } pk;
#pragma unroll
    for (int i = 0; i < 4; ++i) {
      int col = t * 4 + i;
      pk.h[i] = (f16)((v[i] - mean) * rstd * g[col] + be[col]);
    }
    *(uint2*)(out + (size_t)row * W + t * 4) = pk.u;
  } else {
    union { f16 h[2]; unsigned u; } pk;
#pragma unroll
    for (int i = 0; i < 2; ++i) {
      int col = t * 2 + i;
      pk.h[i] = (f16)((v[i] - mean) * rstd * g[col] + be[col]);
    }
    *(unsigned*)(out + (size_t)row * W + t * 2) = pk.u;
  }
}

// ---- GEMM (m97 structure): C(M,N) f16 = A(M,K) @ BT(N,K)^T, 128x128 tile, BK=32 ----
template <int K>
__global__ __launch_bounds__(256, 2) void k_gemm(const f16* __restrict__ A,
                                                 const f16* __restrict__ BT,
                                                 f16* __restrict__ C, int N) {
  __shared__ __align__(16) f16 lA[128 * 32];  // linear (gl_lds requires linear dest)
  __shared__ __align__(16) f16 lB[128 * 32];
  int n0 = blockIdx.x * 128, m0 = blockIdx.y * 128;
  int tid = threadIdx.x, lane = tid & 63, wave = tid >> 6;
  int wr = wave >> 1, wc = wave & 1;
  int fr = lane & 15, kq = (lane >> 4) * 8;
  f32x4 acc[4][4] = {};

  int srow = wave * 32 + (lane >> 2);
  int skel = (lane & 3) * 8;
  const f16* Ap0 = A + (size_t)(m0 + srow) * K + skel;
  const f16* Ap1 = Ap0 + (size_t)16 * K;
  const f16* Bp0 = BT + (size_t)(n0 + srow) * K + skel;
  const f16* Bp1 = Bp0 + (size_t)16 * K;
  f16* lA0 = lA + wave * 1024; f16* lA1 = lA0 + 512;
  f16* lB0 = lB + wave * 1024; f16* lB1 = lB0 + 512;

  for (int k0 = 0; k0 < K; k0 += 32) {
    if (k0) __syncthreads();
    gl16(Ap0 + k0, lA0); gl16(Ap1 + k0, lA1);
    gl16(Bp0 + k0, lB0); gl16(Bp1 + k0, lB1);
    __syncthreads();
    f16x8 af[4], bf[4];
#pragma unroll
    for (int i = 0; i < 4; ++i) af[i] = *(const f16x8*)&lA[(wr * 64 + i * 16 + fr) * 32 + kq];
#pragma unroll
    for (int j = 0; j < 4; ++j) bf[j] = *(const f16x8*)&lB[(wc * 64 + j * 16 + fr) * 32 + kq];
#pragma unroll
    for (int i = 0; i < 4; ++i)
#pragma unroll
      for (int j = 0; j < 4; ++j)
        acc[i][j] = __builtin_amdgcn_mfma_f32_16x16x32_f16(af[i], bf[j], acc[i][j], 0, 0, 0);
  }
  int col = n0 + wc * 64 + fr;
  int rb = m0 + wr * 64 + (lane >> 4) * 4;
#pragma unroll
  for (int i = 0; i < 4; ++i)
#pragma unroll
    for (int j = 0; j < 4; ++j)
#pragma unroll
      for (int r = 0; r < 4; ++r)
        C[(size_t)(rb + i * 16 + r) * N + col + j * 16] = (f16)acc[i][j][r];
}

// ---- SRU scan: 8-deep load ring + 16-deep h ring (store at +8, reuse at +16) ----
// Lifetimes: load(t) issued at body t-8; h(t) computed at body t, stored at body t+8,
// register reused at body t+16. Overwriting h's reg waits on a store 40 vmem-ops old,
// so recent prefetch loads stay in flight (fixes round-4's vmcnt(4) drain).
template <int KK>
__global__ __launch_bounds__(64) void k_scan(const f16* __restrict__ U,
                                             const f16* __restrict__ xln,
                                             const float* __restrict__ wcp,
                                             const float* __restrict__ bp,
                                             f16* __restrict__ yH,
                                             float* __restrict__ cs) {
  int tid = blockIdx.x * 64 + threadIdx.x;  // 0..32767
  int dir = tid >> 14, b = (tid >> 9) & 31, d = tid & 511;
  int col = (dir << 9) + d;
  const int N = 1024 * KK;
  const f16* base = U + dir * (512 * KK) + d;
  const f16* rbase = (KK == 4) ? base + 1536 : xln + col;
  const long rstride = (KK == 4) ? N : 1024;
  float wcf = wcp[col], wcr = wcp[1024 + col];
  float bfv = bp[col], brv = bp[1024 + col];
  float c = 0.f;
  f16 ru0[8], ru1[8], ru2[8], rr[8];
  float hh[16];

  // row of step t: ((dir ? 511-t : t)<<5) + b ; per-step row delta = dir? -32 : +32
  const long sgn = dir ? -32L : 32L;
  const long sN = sgn * N, sR = sgn * rstride, sY = sgn * 1024;
  long row0 = ((long)(dir ? 511 : 0) << 5) + b;
  // prologue: load steps 0..7
  const f16* pL = base + (size_t)row0 * N;
  const f16* pR = rbase + (size_t)row0 * rstride;
#pragma unroll
  for (int i = 0; i < 8; ++i) {
    ru0[i] = pL[0]; ru1[i] = pL[512]; ru2[i] = pL[1024];
    rr[i] = *pR;
    pL += sN; pR += sR;
  }
  f16* pS = yH + (size_t)row0 * 1024 + col;  // store ptr (lags 8 steps behind compute)

#define BODY(i, DO_STORE, DO_PRE)                                        \
  {                                                                      \
    float u0 = (float)ru0[(i) & 7], u1 = (float)ru1[(i) & 7],            \
          u2 = (float)ru2[(i) & 7], res = (float)rr[(i) & 7];            \
    if (DO_STORE) {                                                      \
      *pS = (f16)hh[((i) + 8) & 15];                                     \
      pS += sY;                                                          \
      __builtin_amdgcn_sched_barrier(0); /* pin store before prefetch */ \
    }                                                                    \
    if (DO_PRE) {                                                        \
      ru0[(i) & 7] = pL[0]; ru1[(i) & 7] = pL[512];                      \
      ru2[(i) & 7] = pL[1024]; rr[(i) & 7] = *pR;                        \
      pL += sN; pR += sR;                                                \
    }                                                                    \
    float zf = u1 + wcf * c + bfv;                                       \
    float f = __builtin_amdgcn_rcpf(1.f + __expf(-zf));                  \
    c = f * c + (1.f - f) * u0;                                          \
    float zr = u2 + wcr * c + brv;                                       \
    float r = __builtin_amdgcn_rcpf(1.f + __expf(-zr));                  \
    hh[(i) & 15] = r * c + (1.f - r) * res;                              \
  }

  // iteration 0: t = 0..15 (stores start at body 8 -> h(0..7))
#pragma unroll
  for (int i = 0; i < 16; ++i) BODY(i, (i >= 8), true);
  // steady: t0 = 16..480
  for (int t0 = 16; t0 < 496; t0 += 16) {
#pragma unroll
    for (int i = 0; i < 16; ++i) BODY(i, true, true);
  }
  // final iteration: t = 496..511 (prefetch only for bodies 0..7 -> steps 504..511)
#pragma unroll
  for (int i = 0; i < 16; ++i) BODY(i, true, (i < 8));
  // epilogue: store h(504..511) = hh[8..15]
#pragma unroll
  for (int j = 8; j < 16; ++j) { *pS = (f16)hh[j]; pS += sY; }
  cs[b * 1024 + col] = c;
#undef BODY
}

// ---- lin2 via MFMA: out(M,144) f32 = Y(M,1024) f16 @ WT(144,1024)^T + bias ----
__global__ __launch_bounds__(256) void k_lin2m(const f16* __restrict__ Y,
                                               const f16* __restrict__ WT,
                                               const float* __restrict__ bias,
                                               float* __restrict__ out) {
  __shared__ __align__(16) f16 lA[64 * 32];
  int m0 = blockIdx.x * 64;
  int tid = threadIdx.x, lane = tid & 63, wave = tid >> 6;
  int fr = lane & 15, kq = (lane >> 4) * 8;
  f32x4 acc[9] = {};
  int srow = wave * 16 + (lane >> 2);
  int skel = (lane & 3) * 8;
  const f16* Yp = Y + (size_t)(m0 + srow) * 1024 + skel;
  f16* ldst = lA + wave * 512;
  for (int k0 = 0; k0 < 1024; k0 += 32) {
    if (k0) __syncthreads();
    gl16(Yp + k0, ldst);
    f16x8 bf[9];
#pragma unroll
    for (int j = 0; j < 9; ++j)
      bf[j] = *(const f16x8*)(WT + (size_t)(j * 16 + fr) * 1024 + k0 + kq);
    __syncthreads();
    f16x8 af = *(const f16x8*)&lA[(wave * 16 + fr) * 32 + kq];
#pragma unroll
    for (int j = 0; j < 9; ++j)
      acc[j] = __builtin_amdgcn_mfma_f32_16x16x32_f16(af, bf[j], acc[j], 0, 0, 0);
  }
  int rb = m0 + wave * 16 + (lane >> 4) * 4;
#pragma unroll
  for (int j = 0; j < 9; ++j) {
    float bv = bias[j * 16 + fr];
#pragma unroll
    for (int r = 0; r < 4; ++r)
      out[(size_t)(rb + r) * 144 + j * 16 + fr] = acc[j][r] + bv;
  }
}

extern "C" void kernel_launch(void* const* d_in, const int* in_sizes, int n_in,
                              void* d_out, int out_size, void* d_ws, size_t ws_size,
                              hipStream_t stream) {
  const float* x      = (const float*)d_in[0];
  const float* lin1_w = (const float*)d_in[1];
  const float* lin1_b = (const float*)d_in[2];
  const float* lin2_w = (const float*)d_in[3];
  const float* lin2_b = (const float*)d_in[4];
  const float* W0     = (const float*)d_in[5];
  const float* wc0    = (const float*)d_in[6];
  const float* b0     = (const float*)d_in[7];
  const float* ln0_g  = (const float*)d_in[8];
  const float* ln0_b  = (const float*)d_in[9];
  const float* Wl     = (const float*)d_in[10];
  const float* wcl    = (const float*)d_in[11];
  const float* bl     = (const float*)d_in[12];
  const float* lnl_g  = (const float*)d_in[13];
  const float* lnl_b  = (const float*)d_in[14];
  float* out = (float*)d_out;

  // workspace layout (252 MB)
  char* ws = (char*)d_ws;
  f16* yH  = (f16*)(ws);                       // (16384,1024) f16, 32 MB (scan/lin1 out)
  f16* A16 = (f16*)(ws + ((size_t)32 << 20));  // (16384,1024) f16, 32 MB (LN out)
  f16* C16 = (f16*)(ws + ((size_t)64 << 20));  // (16384,4096) f16, up to 128 MB (U)
  f16* WT2 = (f16*)(ws + ((size_t)192 << 20)); // (144,1024) f16 (free after layer0 scan)
  f16* W0T = (f16*)(ws + ((size_t)224 << 20)); // (4096,512) f16, 4 MB
  f16* WlT = (f16*)(ws + ((size_t)228 << 20)); // 4 x (3072,1024) f16, 24 MB

  k_transpose_perm<4><<<dim3(128, 16, 1), dim3(32, 8), 0, stream>>>(W0, W0T, 512, 4096);
  k_transpose_perm<3><<<dim3(96, 32, 4), dim3(32, 8), 0, stream>>>(Wl, WlT, 1024, 3072);

  k_lin1<<<MM / 8, 256, 0, stream>>>(x, lin1_w, lin1_b, yH);

  // layer 0 (k=4)
  k_ln<512><<<MM, 256, 0, stream>>>(yH, ln0_g, ln0_b, A16);
  k_gemm<512><<<dim3(32, 128), 256, 0, stream>>>(A16, W0T, C16, 4096);
  k_scan<4><<<512, 64, 0, stream>>>(C16, (const f16*)nullptr, wc0, b0, yH, out + 2359296);

  // lin2 weight transpose (into C16 tail, free after layer-0 scan)
  k_transpose2<<<dim3(5, 32), dim3(32, 8), 0, stream>>>(lin2_w, WT2);

  // layers 1..4 (k=3)
  for (int i = 0; i < 4; ++i) {
    k_ln<1024><<<MM, 256, 0, stream>>>(yH, lnl_g + i * 1024, lnl_b + i * 1024, A16);
    k_gemm<1024><<<dim3(24, 128), 256, 0, stream>>>(A16, WlT + (size_t)i * 3072 * 1024, C16, 3072);
    k_scan<3><<<512, 64, 0, stream>>>(C16, A16, wcl + i * 2048, bl + i * 2048, yH,
                                      out + 2359296 + (size_t)(i + 1) * 32768);
  }

  k_lin2m<<<MM / 64, 256, 0, stream>>>(yH, WT2, lin2_b, out);
}